// Round 5
// baseline (279.855 us; speedup 1.0000x reference)
//
#include <hip/hip_runtime.h>
#include <math.h>

#define BB 64
#define RR 6912
#define II 8
#define CC 10
#define OO 16
#define RPB 32          // routes per block
#define NCH 216         // RR / RPB
#define ITERS 4         // RPB / 8 (block covers 8 routes per iter: 4 waves x 2 rr)
#define LDSF (4*32*36)  // epilogue: [wave][bg][36] (16+16 acc, 2 Z, 2 pad)

// ---------------- transpose kernel: x[B][R][8] -> xt[R][B][8] ----------------
__global__ __launch_bounds__(256) void transpose_kernel(
    const float* __restrict__ x, float4* __restrict__ xt4)
{
    __shared__ float4 lds4[64 * 34];
    const int rblk = blockIdx.x >> 2;
    const int bblk = blockIdx.x & 3;
    const int r0 = rblk * 64, b0 = bblk * 16;
    const int t = threadIdx.x;
    {
        const int rl = t & 63;
        const int bl0 = t >> 6;
#pragma unroll
        for (int kb = 0; kb < 4; ++kb) {
            const int bl = kb * 4 + bl0;
            const float4* src = (const float4*)(x + ((size_t)(b0 + bl) * RR + (r0 + rl)) * II);
            lds4[rl * 34 + bl * 2 + 0] = src[0];
            lds4[rl * 34 + bl * 2 + 1] = src[1];
        }
    }
    __syncthreads();
    {
        const int bl = t & 15;
        const int rw0 = t >> 4;
#pragma unroll
        for (int kr = 0; kr < 4; ++kr) {
            const int rw = kr * 16 + rw0;
            float4 a = lds4[rw * 34 + bl * 2 + 0];
            float4 bq = lds4[rw * 34 + bl * 2 + 1];
            float4* dst = xt4 + ((size_t)(r0 + rw) * BB + (b0 + bl)) * 2;
            dst[0] = a; dst[1] = bq;
        }
    }
}

// ---------------- pass kernel ----------------
// lane = (rr = lane>>5, bg = lane&31); thread handles batches b=bg and b=bg+32
// for route r = chunk*RPB + it*8 + wave*2 + rr. W loads are per-lane vector
// loads (2 distinct addrs/inst), reused across 2 batches x 16 o in registers.
// No LDS / no barriers in the main loop. No max-subtraction in softmax
// (|logit| small enough for fp32 exp; identical math to reference).
#define FMAQ(P, XS, W) { P[0]=fmaf(XS,W.x,P[0]); P[1]=fmaf(XS,W.y,P[1]); \
                         P[2]=fmaf(XS,W.z,P[2]); P[3]=fmaf(XS,W.w,P[3]); }
#define ISTEP(XS0, XS1, BASE) { \
    float4 w0 = wr[BASE+0], w1 = wr[BASE+1], w2 = wr[BASE+2], w3 = wr[BASE+3]; \
    FMAQ((t0+0),XS0,w0) FMAQ((t0+4),XS0,w1) FMAQ((t0+8),XS0,w2) FMAQ((t0+12),XS0,w3) \
    FMAQ((t1+0),XS1,w0) FMAQ((t1+4),XS1,w1) FMAQ((t1+8),XS1,w2) FMAQ((t1+12),XS1,w3) }

template <int MODE>
__global__ __launch_bounds__(256, 2) void pass_kernel(
    const float4* __restrict__ xt4, const float4* __restrict__ w4,
    const float* __restrict__ ov_in,
    float* __restrict__ pacc, float* __restrict__ pz)
{
    __shared__ __align__(16) float lds[LDSF];

    const int bid = blockIdx.x;
    const int c = bid / NCH;
    const int chunk = bid - c * NCH;
    const int t = threadIdx.x;
    const int wv = t >> 6;
    const int lane = t & 63;
    const int rr = lane >> 5;
    const int bg = lane & 31;

    float acc0[OO], acc1[OO];
#pragma unroll
    for (int o = 0; o < OO; ++o) { acc0[o] = 0.f; acc1[o] = 0.f; }
    float Z0 = 0.f, Z1 = 0.f;

    float ov0[OO], ov1[OO];
    if (MODE != 0) {
        const float4* opa = (const float4*)(ov_in + ((size_t)c * BB + bg) * OO);
        const float4* opb = (const float4*)(ov_in + ((size_t)c * BB + bg + 32) * OO);
#pragma unroll
        for (int q = 0; q < 4; ++q) {
            float4 va = opa[q], vb = opb[q];
            ov0[q*4+0]=va.x; ov0[q*4+1]=va.y; ov0[q*4+2]=va.z; ov0[q*4+3]=va.w;
            ov1[q*4+0]=vb.x; ov1[q*4+1]=vb.y; ov1[q*4+2]=vb.z; ov1[q*4+3]=vb.w;
        }
    }

    const int rbase = chunk * RPB + wv * 2 + rr;

#pragma unroll 1
    for (int it = 0; it < ITERS; ++it) {
        const int r = rbase + it * 8;
        // x for (r, bg) and (r, bg+32): coalesced per-lane float4 pairs
        const float4* xp = xt4 + ((size_t)r * BB + bg) * 2;
        const float4 xA0 = xp[0],  xA1 = xp[1];     // b = bg
        const float4 xB0 = xp[64], xB1 = xp[65];    // b = bg+32

        const float4* __restrict__ wr = w4 + ((size_t)c * RR + r) * 32;

        float p0[OO], p1[OO];
        float (&t0)[OO] = (MODE == 0) ? acc0 : p0;
        float (&t1)[OO] = (MODE == 0) ? acc1 : p1;
        if (MODE != 0) {
#pragma unroll
            for (int o = 0; o < OO; ++o) { p0[o] = 0.f; p1[o] = 0.f; }
        }

        ISTEP(xA0.x, xB0.x, 0)  ISTEP(xA0.y, xB0.y, 4)
        ISTEP(xA0.z, xB0.z, 8)  ISTEP(xA0.w, xB0.w, 12)
        ISTEP(xA1.x, xB1.x, 16) ISTEP(xA1.y, xB1.y, 20)
        ISTEP(xA1.z, xB1.z, 24) ISTEP(xA1.w, xB1.w, 28)

        if (MODE != 0) {
            float d0 = 0.f, d1 = 0.f;
#pragma unroll
            for (int o = 0; o < OO; ++o) { d0 = fmaf(p0[o], ov0[o], d0); d1 = fmaf(p1[o], ov1[o], d1); }
            const float e0 = __expf(d0), e1 = __expf(d1);
            Z0 += e0; Z1 += e1;
#pragma unroll
            for (int o = 0; o < OO; ++o) { acc0[o] = fmaf(e0, p0[o], acc0[o]); acc1[o] = fmaf(e1, p1[o], acc1[o]); }
        }
    }

    // reduce across rr (lane ^ 32)
#pragma unroll
    for (int o = 0; o < OO; ++o) {
        acc0[o] += __shfl_xor(acc0[o], 32);
        acc1[o] += __shfl_xor(acc1[o], 32);
    }
    if (MODE != 0) { Z0 += __shfl_xor(Z0, 32); Z1 += __shfl_xor(Z1, 32); }

    if (rr == 0) {
        float* s = lds + (wv * 32 + bg) * 36;
#pragma unroll
        for (int o = 0; o < OO; ++o) { s[o] = acc0[o]; s[16 + o] = acc1[o]; }
        s[32] = Z0; s[33] = Z1;
    }
    __syncthreads();

    // final block reduce: thread t -> (b = t>>2, o-quad q = t&3)
    {
        const int b = t >> 2, q = t & 3;
        const int k = b >> 5, bgf = b & 31;
        float4 sum = make_float4(0.f, 0.f, 0.f, 0.f);
#pragma unroll
        for (int w2 = 0; w2 < 4; ++w2) {
            const float4 v = *(const float4*)(lds + (w2 * 32 + bgf) * 36 + k * 16 + q * 4);
            sum.x += v.x; sum.y += v.y; sum.z += v.z; sum.w += v.w;
        }
        *(float4*)(pacc + (((size_t)(c * NCH + chunk) * BB + b) * OO) + q * 4) = sum;
        if (MODE != 0 && q == 0) {
            float z = 0.f;
#pragma unroll
            for (int w2 = 0; w2 < 4; ++w2) z += lds[(w2 * 32 + bgf) * 36 + 32 + k];
            pz[(size_t)(c * NCH + chunk) * BB + b] = z;
        }
    }
}

// ---------------- combine kernel ----------------
// One block per (c,b). 256 threads = 16 o x 16 groups. Plain sums (no max).
// MODE 0: s = sum/R -> out0 = squash(s)
// MODE 1: outsum = out0 + squash(sum/Z)
// MODE 2: final  = squash(sum/Z)
template <int MODE>
__global__ __launch_bounds__(256) void combine_kernel(
    const float* __restrict__ pacc, const float* __restrict__ pz,
    const float* __restrict__ out0, float* __restrict__ outw)
{
    __shared__ float lsum[256];
    __shared__ float lz[16];
    const int cb = blockIdx.x;
    const int c = cb >> 6, b = cb & 63;
    const int t = threadIdx.x;
    const int o = t & 15, g = t >> 4;

    float s = 0.f, zl = 0.f;
    for (int p = g; p < NCH; p += 16) {
        s += pacc[((size_t)(c * NCH + p) * BB + b) * OO + o];
        if (MODE != 0 && o == 0) zl += pz[(size_t)(c * NCH + p) * BB + b];
    }
    lsum[t] = s;
    if (MODE != 0 && o == 0) lz[g] = zl;
    __syncthreads();

    if (g == 0) {
#pragma unroll
        for (int k = 1; k < 16; ++k) s += lsum[k * 16 + o];
        if (MODE != 0) {
            float Zt = 0.f;
#pragma unroll
            for (int k = 0; k < 16; ++k) Zt += lz[k];
            s /= Zt;
        } else {
            s *= (1.0f / RR);
        }
        float sq = s * s;
#pragma unroll
        for (int w = 1; w < 16; w <<= 1) sq += __shfl_xor(sq, w);
        float val = s * sqrtf(sq) / (1.f + sq);
        if (MODE == 1) val += out0[(size_t)cb * OO + o];
        outw[(size_t)cb * OO + o] = val;
    }
}

extern "C" void kernel_launch(void* const* d_in, const int* in_sizes, int n_in,
                              void* d_out, int out_size, void* d_ws, size_t ws_size,
                              hipStream_t stream)
{
    const float* x = (const float*)d_in[0];
    const float* w = (const float*)d_in[1];
    float* out = (float*)d_out;

    float* ws = (float*)d_ws;
    float* xt     = ws;                                   // RR*BB*II
    float* pacc   = xt + (size_t)RR * BB * II;            // CC*NCH*BB*OO
    float* pz     = pacc + (size_t)CC * NCH * BB * OO;    // CC*NCH*BB
    float* out0   = pz + (size_t)CC * NCH * BB;           // CC*BB*OO
    float* outsum = out0 + CC * BB * OO;                  // CC*BB*OO

    float4* xt4 = (float4*)xt;
    const float4* w4 = (const float4*)w;

    transpose_kernel<<<dim3((RR / 64) * 4), dim3(256), 0, stream>>>(x, xt4);

    const dim3 gp(CC * NCH), bp(256);
    const dim3 gc(CC * BB), bc(256);

    pass_kernel<0><<<gp, bp, 0, stream>>>(xt4, w4, nullptr, pacc, pz);
    combine_kernel<0><<<gc, bc, 0, stream>>>(pacc, pz, nullptr, out0);
    pass_kernel<1><<<gp, bp, 0, stream>>>(xt4, w4, out0, pacc, pz);
    combine_kernel<1><<<gc, bc, 0, stream>>>(pacc, pz, out0, outsum);
    pass_kernel<2><<<gp, bp, 0, stream>>>(xt4, w4, outsum, pacc, pz);
    combine_kernel<2><<<gc, bc, 0, stream>>>(pacc, pz, nullptr, out);
}

// Round 6
// 171.385 us; speedup vs baseline: 1.6329x; 1.6329x over previous
//
#include <hip/hip_runtime.h>
#include <math.h>

#define BB 64
#define RR 6912
#define II 8
#define CC 10
#define OO 16
#define RPB 32          // routes per block (chunk)
#define NCH 216         // RR / RPB
#define NIT 4           // iters per chunk; each iter covers 8 routes (4 waves x 2 rr)
#define LDSF (4*32*36)  // epilogue floats (18432 B); W tile (2 KB) aliases this

typedef _Float16 h2 __attribute__((ext_vector_type(2)));
union HV { int4 v; h2 h[4]; };

// ---------------- transpose+cvt kernel: x[B][R][8] f32 -> xth[R][B][8] f16 ----------------
__global__ __launch_bounds__(256) void transpose_cvt_kernel(
    const float* __restrict__ x, int4* __restrict__ xth4)
{
    __shared__ float4 lds4[64 * 34];
    const int rblk = blockIdx.x >> 2;
    const int bblk = blockIdx.x & 3;
    const int r0 = rblk * 64, b0 = bblk * 16;
    const int t = threadIdx.x;
    {
        const int rl = t & 63;
        const int bl0 = t >> 6;
#pragma unroll
        for (int kb = 0; kb < 4; ++kb) {
            const int bl = kb * 4 + bl0;
            const float4* src = (const float4*)(x + ((size_t)(b0 + bl) * RR + (r0 + rl)) * II);
            lds4[rl * 34 + bl * 2 + 0] = src[0];
            lds4[rl * 34 + bl * 2 + 1] = src[1];
        }
    }
    __syncthreads();
    {
        const int bl = t & 15;
        const int rw0 = t >> 4;
#pragma unroll
        for (int kr = 0; kr < 4; ++kr) {
            const int rw = kr * 16 + rw0;
            float4 a = lds4[rw * 34 + bl * 2 + 0];
            float4 bq = lds4[rw * 34 + bl * 2 + 1];
            HV u;
            u.h[0] = h2{(_Float16)a.x,  (_Float16)a.y};
            u.h[1] = h2{(_Float16)a.z,  (_Float16)a.w};
            u.h[2] = h2{(_Float16)bq.x, (_Float16)bq.y};
            u.h[3] = h2{(_Float16)bq.z, (_Float16)bq.w};
            xth4[(size_t)(r0 + rw) * BB + (b0 + bl)] = u.v;
        }
    }
}

// ---------------- pass kernel ----------------
// Wave wv covers routes r0+wv*2+{0,1} (rr = lane>>5); each thread handles
// batches bg and bg+32 (bg = lane&31). W staged to LDS as f16 [route][o][i]
// (converted from f32 during staging); compute via v_dot2_f32_f16.
// MODE 0: plain sum of priors; MODE 1/2: softmax-weighted (no max-subtraction:
// |logit| <= ~50, exp fits fp32 -- validated exactly in R5).
template <int MODE>
__global__ __launch_bounds__(256, 2) void pass_kernel(
    const int4* __restrict__ xth4, const float* __restrict__ w,
    const float* __restrict__ ov_in,
    float* __restrict__ pacc, float* __restrict__ pz)
{
    __shared__ __align__(16) float lds[LDSF];
    int4* wlds = (int4*)lds;           // 128 int4 = 8 routes x 16 o x (8 i f16)

    const int bid = blockIdx.x;
    const int c = bid / NCH;
    const int chunk = bid - c * NCH;
    const int t = threadIdx.x;
    const int wv = t >> 6;
    const int lane = t & 63;
    const int rr = lane >> 5;
    const int bg = lane & 31;

    float acc0[OO], acc1[OO];
#pragma unroll
    for (int o = 0; o < OO; ++o) { acc0[o] = 0.f; acc1[o] = 0.f; }
    float Z0 = 0.f, Z1 = 0.f;

    float ov0[OO], ov1[OO];
    if (MODE != 0) {
        const float4* opa = (const float4*)(ov_in + ((size_t)c * BB + bg) * OO);
        const float4* opb = (const float4*)(ov_in + ((size_t)c * BB + bg + 32) * OO);
#pragma unroll
        for (int q = 0; q < 4; ++q) {
            float4 va = opa[q], vb = opb[q];
            ov0[q*4+0]=va.x; ov0[q*4+1]=va.y; ov0[q*4+2]=va.z; ov0[q*4+3]=va.w;
            ov1[q*4+0]=vb.x; ov1[q*4+1]=vb.y; ov1[q*4+2]=vb.z; ov1[q*4+3]=vb.w;
        }
    }

#pragma unroll 1
    for (int it = 0; it < NIT; ++it) {
        const int r0 = chunk * RPB + it * 8;
        __syncthreads();
        if (t < 128) {
            // stage W[c, r0+rp, :, o] -> f16 [rp][o][i] (transpose i<->o + cvt)
            const int rp = t >> 4, o = t & 15;
            const float* src = w + (size_t)(c * RR + r0 + rp) * 128 + o;
            const float f0 = src[0],  f1 = src[16], f2 = src[32], f3 = src[48];
            const float f4 = src[64], f5 = src[80], f6 = src[96], f7 = src[112];
            HV u;
            u.h[0] = h2{(_Float16)f0, (_Float16)f1};
            u.h[1] = h2{(_Float16)f2, (_Float16)f3};
            u.h[2] = h2{(_Float16)f4, (_Float16)f5};
            u.h[3] = h2{(_Float16)f6, (_Float16)f7};
            wlds[t] = u.v;
        }
        __syncthreads();

        const int r = r0 + wv * 2 + rr;
        HV xa, xb;
        xa.v = xth4[(size_t)r * BB + bg];
        xb.v = xth4[(size_t)r * BB + bg + 32];

        float p0[OO], p1[OO];
#pragma unroll
        for (int o = 0; o < OO; ++o) {
            HV wq; wq.v = wlds[(wv * 2 + rr) * 16 + o];
            float a = __builtin_amdgcn_fdot2(xa.h[0], wq.h[0],
                        (MODE == 0) ? acc0[o] : 0.f, false);
            a = __builtin_amdgcn_fdot2(xa.h[1], wq.h[1], a, false);
            a = __builtin_amdgcn_fdot2(xa.h[2], wq.h[2], a, false);
            a = __builtin_amdgcn_fdot2(xa.h[3], wq.h[3], a, false);
            float bb = __builtin_amdgcn_fdot2(xb.h[0], wq.h[0],
                        (MODE == 0) ? acc1[o] : 0.f, false);
            bb = __builtin_amdgcn_fdot2(xb.h[1], wq.h[1], bb, false);
            bb = __builtin_amdgcn_fdot2(xb.h[2], wq.h[2], bb, false);
            bb = __builtin_amdgcn_fdot2(xb.h[3], wq.h[3], bb, false);
            if (MODE == 0) { acc0[o] = a; acc1[o] = bb; }
            else           { p0[o] = a;   p1[o] = bb; }
        }

        if (MODE != 0) {
            float d0 = 0.f, d1 = 0.f;
#pragma unroll
            for (int o = 0; o < OO; ++o) { d0 = fmaf(p0[o], ov0[o], d0); d1 = fmaf(p1[o], ov1[o], d1); }
            const float e0 = __expf(d0), e1 = __expf(d1);
            Z0 += e0; Z1 += e1;
#pragma unroll
            for (int o = 0; o < OO; ++o) { acc0[o] = fmaf(e0, p0[o], acc0[o]); acc1[o] = fmaf(e1, p1[o], acc1[o]); }
        }
    }

    // reduce across rr (lane ^ 32): sums the two routes of this wave
#pragma unroll
    for (int o = 0; o < OO; ++o) {
        acc0[o] += __shfl_xor(acc0[o], 32);
        acc1[o] += __shfl_xor(acc1[o], 32);
    }
    if (MODE != 0) { Z0 += __shfl_xor(Z0, 32); Z1 += __shfl_xor(Z1, 32); }

    __syncthreads();
    if (rr == 0) {
        float* s = lds + (wv * 32 + bg) * 36;
#pragma unroll
        for (int o = 0; o < OO; ++o) { s[o] = acc0[o]; s[16 + o] = acc1[o]; }
        s[32] = Z0; s[33] = Z1;
    }
    __syncthreads();

    // final block reduce: thread t -> (b = t>>2, o-quad q = t&3)
    {
        const int b = t >> 2, q = t & 3;
        const int k = b >> 5, bgf = b & 31;
        float4 sum = make_float4(0.f, 0.f, 0.f, 0.f);
#pragma unroll
        for (int w2 = 0; w2 < 4; ++w2) {
            const float4 v = *(const float4*)(lds + (w2 * 32 + bgf) * 36 + k * 16 + q * 4);
            sum.x += v.x; sum.y += v.y; sum.z += v.z; sum.w += v.w;
        }
        *(float4*)(pacc + (((size_t)(c * NCH + chunk) * BB + b) * OO) + q * 4) = sum;
        if (MODE != 0 && q == 0) {
            float z = 0.f;
#pragma unroll
            for (int w2 = 0; w2 < 4; ++w2) z += lds[(w2 * 32 + bgf) * 36 + 32 + k];
            pz[(size_t)(c * NCH + chunk) * BB + b] = z;
        }
    }
}

// ---------------- combine kernel ----------------
// One block per (c,b). 256 threads = 16 o x 16 groups. Plain sums (no max).
// MODE 0: s = sum/R -> out0 = squash(s)
// MODE 1: outsum = out0 + squash(sum/Z)
// MODE 2: final  = squash(sum/Z)
template <int MODE>
__global__ __launch_bounds__(256) void combine_kernel(
    const float* __restrict__ pacc, const float* __restrict__ pz,
    const float* __restrict__ out0, float* __restrict__ outw)
{
    __shared__ float lsum[256];
    __shared__ float lz[16];
    const int cb = blockIdx.x;
    const int c = cb >> 6, b = cb & 63;
    const int t = threadIdx.x;
    const int o = t & 15, g = t >> 4;

    float s = 0.f, zl = 0.f;
    for (int p = g; p < NCH; p += 16) {
        s += pacc[((size_t)(c * NCH + p) * BB + b) * OO + o];
        if (MODE != 0 && o == 0) zl += pz[(size_t)(c * NCH + p) * BB + b];
    }
    lsum[t] = s;
    if (MODE != 0 && o == 0) lz[g] = zl;
    __syncthreads();

    if (g == 0) {
#pragma unroll
        for (int k = 1; k < 16; ++k) s += lsum[k * 16 + o];
        if (MODE != 0) {
            float Zt = 0.f;
#pragma unroll
            for (int k = 0; k < 16; ++k) Zt += lz[k];
            s /= Zt;
        } else {
            s *= (1.0f / RR);
        }
        float sq = s * s;
#pragma unroll
        for (int w = 1; w < 16; w <<= 1) sq += __shfl_xor(sq, w);
        float val = s * sqrtf(sq) / (1.f + sq);
        if (MODE == 1) val += out0[(size_t)cb * OO + o];
        outw[(size_t)cb * OO + o] = val;
    }
}

extern "C" void kernel_launch(void* const* d_in, const int* in_sizes, int n_in,
                              void* d_out, int out_size, void* d_ws, size_t ws_size,
                              hipStream_t stream)
{
    const float* x = (const float*)d_in[0];
    const float* w = (const float*)d_in[1];
    float* out = (float*)d_out;

    float* ws = (float*)d_ws;
    float* xth    = ws;                                   // RR*BB*8 f16 = RR*BB*4 floats
    float* pacc   = xth + (size_t)RR * BB * 4;            // CC*NCH*BB*OO
    float* pz     = pacc + (size_t)CC * NCH * BB * OO;    // CC*NCH*BB
    float* out0   = pz + (size_t)CC * NCH * BB;           // CC*BB*OO
    float* outsum = out0 + CC * BB * OO;                  // CC*BB*OO

    int4* xth4 = (int4*)xth;

    transpose_cvt_kernel<<<dim3((RR / 64) * 4), dim3(256), 0, stream>>>(x, xth4);

    const dim3 gp(CC * NCH), bp(256);
    const dim3 gc(CC * BB), bc(256);

    pass_kernel<0><<<gp, bp, 0, stream>>>(xth4, w, nullptr, pacc, pz);
    combine_kernel<0><<<gc, bc, 0, stream>>>(pacc, pz, nullptr, out0);
    pass_kernel<1><<<gp, bp, 0, stream>>>(xth4, w, out0, pacc, pz);
    combine_kernel<1><<<gc, bc, 0, stream>>>(pacc, pz, out0, outsum);
    pass_kernel<2><<<gp, bp, 0, stream>>>(xth4, w, outsum, pacc, pz);
    combine_kernel<2><<<gc, bc, 0, stream>>>(pacc, pz, nullptr, out);
}